// Round 1
// baseline (25.475 us; speedup 1.0000x reference)
//
#include <hip/hip_runtime.h>

#define NRAYS 16384
#define NB 129   // bin edges / samples per ray
#define NW 128   // weights / intervals per ray
#define RPB 2    // rays per block (256 threads)

__global__ __launch_bounds__(256) void mipnerf_resample_kernel(
    const float* __restrict__ origins,     // [B,3]
    const float* __restrict__ directions,  // [B,3]
    const float* __restrict__ radii,       // [B,1]
    const float* __restrict__ t_vals,      // [B,129]
    const float* __restrict__ weights,     // [B,128]
    float* __restrict__ out_t,             // [B,129]
    float* __restrict__ out_means,         // [B,128,3]
    float* __restrict__ out_covs)          // [B,128,3]
{
    __shared__ float s_t[RPB][NB];    // original bins
    __shared__ float s_w[RPB][NW];    // raw weights -> blurred -> prefix sums
    __shared__ float s_cdf[RPB][NB];
    __shared__ float s_nt[RPB][NB];   // resampled t

    const int tid = threadIdx.x;
    const int rg  = tid >> 7;     // ray slot within block
    const int r   = tid & 127;    // lane within ray (0..127)
    const int ray = blockIdx.x * RPB + rg;

    // ---- stage inputs ----
    const float w_r = weights[(long)ray * NW + r];
    s_w[rg][r] = w_r;
    s_t[rg][r] = t_vals[(long)ray * NB + r];
    if (r == 0) s_t[rg][NB - 1] = t_vals[(long)ray * NB + NB - 1];
    __syncthreads();

    // ---- max-blur + padding: w = 0.5*(max(w[i-1],w[i]) + max(w[i],w[i+1])) + 0.01 ----
    const int im1 = (r > 0) ? r - 1 : 0;
    const int ip1 = (r < NW - 1) ? r + 1 : NW - 1;
    const float wb = 0.5f * (fmaxf(s_w[rg][im1], w_r) + fmaxf(w_r, s_w[rg][ip1])) + 0.01f;
    __syncthreads();
    s_w[rg][r] = wb;
    __syncthreads();

    // ---- inclusive Hillis-Steele scan over the 128 blurred weights ----
    #pragma unroll
    for (int off = 1; off < NW; off <<= 1) {
        const float v = (r >= off) ? s_w[rg][r - off] : 0.0f;
        __syncthreads();
        s_w[rg][r] += v;
        __syncthreads();
    }
    const float wsum = s_w[rg][NW - 1];
    // (eps-pad branch of the reference is identically zero: every w >= 0.01 -> wsum >= 1.28 >> 1e-5)

    // ---- cdf[129] = [0, min(1, W[k-1]/wsum) for k=1..127, 1] ----
    if (r == 0) { s_cdf[rg][0] = 0.0f; s_cdf[rg][NB - 1] = 1.0f; }
    if (r < NW - 1) s_cdf[rg][r + 1] = fminf(1.0f, s_w[rg][r] / wsum);
    __syncthreads();

    // ---- inverse-CDF sampling: u = linspace(0, 1-eps, 129), searchsorted 'right' ----
    const float ueps = 1.0f - 1.1920929e-7f;
    const float step = ueps / 128.0f;
    for (int s = r; s < NB; s += NW) {   // thread r does sample r; thread 0 also does sample 128
        const float u = (s == NB - 1) ? ueps : (float)s * step;
        int lo = 0, hi = NB;
        while (lo < hi) {
            const int mid = (lo + hi) >> 1;
            if (s_cdf[rg][mid] <= u) lo = mid + 1; else hi = mid;
        }
        int i1 = lo; if (i1 < 1) i1 = 1; if (i1 > NB - 1) i1 = NB - 1;
        const int i0 = i1 - 1;
        const float c0 = s_cdf[rg][i0], c1 = s_cdf[rg][i1];
        const float b0 = s_t[rg][i0],  b1 = s_t[rg][i1];
        float tt = (u - c0) / (c1 - c0);
        if (tt != tt) tt = 0.0f;                 // NaN -> 0 (matches nan_to_num then clip)
        tt = fminf(fmaxf(tt, 0.0f), 1.0f);       // inf clips to 1, matching reference
        const float nt = fmaf(tt, b1 - b0, b0);
        s_nt[rg][s] = nt;
        out_t[(long)ray * NB + s] = nt;
    }
    __syncthreads();

    // ---- conical frustum -> Gaussian per interval ----
    const float t0 = s_nt[rg][r], t1 = s_nt[rg][r + 1];
    const float mu = 0.5f * (t0 + t1), hw = 0.5f * (t1 - t0);
    const float mu2 = mu * mu, hw2 = hw * hw;
    const float denom = 3.0f * mu2 + hw2;
    const float inv_denom = 1.0f / denom;
    const float t_mean = mu + 2.0f * mu * hw2 * inv_denom;
    const float t_var  = hw2 * (1.0f / 3.0f)
                       - (4.0f / 15.0f) * (hw2 * hw2 * (12.0f * mu2 - hw2) * inv_denom * inv_denom);
    const float rad = radii[ray];
    const float r_var = rad * rad * (0.25f * mu2 + (5.0f / 12.0f) * hw2
                                     - (4.0f / 15.0f) * hw2 * hw2 * inv_denom);

    const float dx = directions[(long)ray * 3 + 0];
    const float dy = directions[(long)ray * 3 + 1];
    const float dz = directions[(long)ray * 3 + 2];
    const float ox = origins[(long)ray * 3 + 0];
    const float oy = origins[(long)ray * 3 + 1];
    const float oz = origins[(long)ray * 3 + 2];
    const float dms = dx * dx + dy * dy + dz * dz + 1e-10f;
    const float inv_dms = 1.0f / dms;

    const long base = ((long)ray * NW + r) * 3;
    out_means[base + 0] = fmaf(dx, t_mean, ox);
    out_means[base + 1] = fmaf(dy, t_mean, oy);
    out_means[base + 2] = fmaf(dz, t_mean, oz);
    out_covs[base + 0] = t_var * dx * dx + r_var * (1.0f - dx * dx * inv_dms);
    out_covs[base + 1] = t_var * dy * dy + r_var * (1.0f - dy * dy * inv_dms);
    out_covs[base + 2] = t_var * dz * dz + r_var * (1.0f - dz * dz * inv_dms);
}

extern "C" void kernel_launch(void* const* d_in, const int* in_sizes, int n_in,
                              void* d_out, int out_size, void* d_ws, size_t ws_size,
                              hipStream_t stream) {
    const float* origins    = (const float*)d_in[0];
    const float* directions = (const float*)d_in[1];
    const float* radii      = (const float*)d_in[2];
    const float* t_vals     = (const float*)d_in[3];
    const float* weights    = (const float*)d_in[4];

    float* out_t     = (float*)d_out;
    float* out_means = out_t + (long)NRAYS * NB;
    float* out_covs  = out_means + (long)NRAYS * NW * 3;

    const int grid = NRAYS / RPB;  // 8192 blocks of 256 threads
    mipnerf_resample_kernel<<<grid, 256, 0, stream>>>(
        origins, directions, radii, t_vals, weights, out_t, out_means, out_covs);
}

// Round 2
// 24.304 us; speedup vs baseline: 1.0482x; 1.0482x over previous
//
#include <hip/hip_runtime.h>

#define NRAYS 16384
#define NB 129   // bin edges / samples per ray
#define NW 128   // weights / intervals per ray

// One wave (64 lanes) per ray; 4 rays per 256-thread block.
__global__ __launch_bounds__(256) void mipnerf_wave_kernel(
    const float* __restrict__ origins,     // [B,3]
    const float* __restrict__ directions,  // [B,3]
    const float* __restrict__ radii,       // [B,1]
    const float* __restrict__ t_vals,      // [B,129]
    const float* __restrict__ weights,     // [B,128]
    float* __restrict__ out_t,             // [B,129]
    float* __restrict__ out_means,         // [B,128,3]
    float* __restrict__ out_covs)          // [B,128,3]
{
    __shared__ float s_t[4][NB];    // original bins (random access in interp)
    __shared__ float s_cdf[4][NB];  // cdf (random access in binary search)

    const int tid = threadIdx.x;
    const int wv  = tid >> 6;      // wave slot = ray slot in block
    const int l   = tid & 63;      // lane
    const int ray = (blockIdx.x << 2) + wv;
    const long tbase = (long)ray * NB;

    // ---- stage bins to LDS (scalar: 129-float rows break float2 alignment on odd rays) ----
    s_t[wv][l]      = t_vals[tbase + l];
    s_t[wv][64 + l] = t_vals[tbase + 64 + l];
    if (l == 63) s_t[wv][128] = t_vals[tbase + 128];

    // ---- weights: float2 per lane (row stride 512B keeps alignment) ----
    const float2 wp = *reinterpret_cast<const float2*>(weights + (long)ray * NW + 2 * l);
    const float r0 = wp.x, r1 = wp.y;             // w[2l], w[2l+1]
    float wm1 = __shfl_up(r0 * 0.0f + r1, 1);     // w[2l-1] from prev lane
    if (l == 0) wm1 = r0;                         // clamp at left edge
    float wp1 = __shfl_down(r0, 1);               // w[2l+2] from next lane
    if (l == 63) wp1 = r1;                        // clamp at right edge

    // max-blur + resample padding
    const float mx01 = fmaxf(r0, r1);
    const float wb0 = 0.5f * (fmaxf(wm1, r0) + mx01) + 0.01f;
    const float wb1 = 0.5f * (mx01 + fmaxf(r1, wp1)) + 0.01f;

    // ---- wave-wide inclusive scan of pair sums (6 shuffle steps, no barriers) ----
    float S = wb0 + wb1;
    #pragma unroll
    for (int off = 1; off < 64; off <<= 1) {
        const float t = __shfl_up(S, off);
        if (l >= off) S += t;
    }
    const float W1 = S;          // inclusive prefix through w[2l+1]
    const float W0 = S - wb1;    // inclusive prefix through w[2l]
    const float wsum = __shfl(S, 63);
    // eps-pad branch of reference is identically 0: every wb >= 0.01 -> wsum >= 1.28

    // cdf[k] = min(1, W[k-1]/wsum), k=1..127; cdf[0]=0; cdf[128]=1
    s_cdf[wv][2 * l + 1] = fminf(1.0f, W0 / wsum);
    if (l < 63) s_cdf[wv][2 * l + 2] = fminf(1.0f, W1 / wsum);
    if (l == 0)  s_cdf[wv][0]   = 0.0f;
    if (l == 63) s_cdf[wv][128] = 1.0f;
    __syncthreads();   // the only barrier: publish s_t + s_cdf across compiler/wave boundary

    // ---- inverse-CDF sampling: searchsorted(cdf, u, 'right') + lerp ----
    const float ueps = 1.0f - 1.1920929e-7f;
    const float step = ueps / 128.0f;
    const float* cdf = s_cdf[wv];
    const float* bins = s_t[wv];

    auto sampleAt = [&](float u) -> float {
        int lo = 0, hi = NB;
        while (lo < hi) {                      // first idx with cdf[idx] > u
            const int mid = (lo + hi) >> 1;
            if (cdf[mid] <= u) lo = mid + 1; else hi = mid;
        }
        const int i1 = lo;                     // in [1,128]: cdf[0]=0<=u, cdf[128]=1>u
        const int i0 = i1 - 1;
        const float c0 = cdf[i0], c1 = cdf[i1];
        const float b0 = bins[i0], b1 = bins[i1];
        float tt = (u - c0) / (c1 - c0);
        if (tt != tt) tt = 0.0f;               // nan_to_num
        tt = fminf(fmaxf(tt, 0.0f), 1.0f);     // clip (inf -> 1, matching reference)
        return fmaf(tt, b1 - b0, b0);
    };

    // samples l and l+64 per lane -> out_t stores are stride-4 contiguous
    const float nt0 = sampleAt((float)l * step);
    const float nt1 = sampleAt((float)(64 + l) * step);
    out_t[tbase + l]      = nt0;
    out_t[tbase + 64 + l] = nt1;
    float nt2 = 0.0f;
    if (l == 63) { nt2 = sampleAt(ueps); out_t[tbase + 128] = nt2; }

    // ---- gather nt[2l], nt[2l+1], nt[2l+2] via shuffles (no LDS, no barrier) ----
    const int sl0 = (2 * l) & 63, sl1 = (2 * l + 1) & 63, sl2 = (2 * l + 2) & 63;
    const float x0 = __shfl(nt0, sl0), x1 = __shfl(nt1, sl0);
    const float y0 = __shfl(nt0, sl1), y1 = __shfl(nt1, sl1);
    const float z0 = __shfl(nt0, sl2), z1 = __shfl(nt1, sl2), z2 = __shfl(nt2, 63);
    const float n0 = (l < 32) ? x0 : x1;                       // nt[2l]
    const float n1 = (l < 32) ? y0 : y1;                       // nt[2l+1]
    const float n2 = (l < 31) ? z0 : ((l < 63) ? z1 : z2);     // nt[2l+2]

    // ---- per-ray scalars (same-address loads broadcast) ----
    const float dx = directions[ray * 3 + 0];
    const float dy = directions[ray * 3 + 1];
    const float dz = directions[ray * 3 + 2];
    const float ox = origins[ray * 3 + 0];
    const float oy = origins[ray * 3 + 1];
    const float oz = origins[ray * 3 + 2];
    const float rad = radii[ray];
    const float rad2 = rad * rad;
    const float dx2 = dx * dx, dy2 = dy * dy, dz2 = dz * dz;
    const float inv_dms = 1.0f / (dx2 + dy2 + dz2 + 1e-10f);
    const float nx = 1.0f - dx2 * inv_dms;
    const float ny = 1.0f - dy2 * inv_dms;
    const float nz = 1.0f - dz2 * inv_dms;

    // ---- conical frustum -> Gaussian for intervals 2l and 2l+1 ----
    float tm[2], tv[2], rv[2];
    const float tt0[2] = { n0, n1 };
    const float tt1[2] = { n1, n2 };
    #pragma unroll
    for (int k = 0; k < 2; ++k) {
        const float mu = 0.5f * (tt0[k] + tt1[k]);
        const float hw = 0.5f * (tt1[k] - tt0[k]);
        const float mu2 = mu * mu, hw2 = hw * hw;
        const float inv_denom = 1.0f / (3.0f * mu2 + hw2);
        tm[k] = mu + 2.0f * mu * hw2 * inv_denom;
        tv[k] = hw2 * (1.0f / 3.0f)
              - (4.0f / 15.0f) * (hw2 * hw2 * (12.0f * mu2 - hw2) * inv_denom * inv_denom);
        rv[k] = rad2 * (0.25f * mu2 + (5.0f / 12.0f) * hw2
                        - (4.0f / 15.0f) * hw2 * hw2 * inv_denom);
    }

    // ---- stores: 6 contiguous floats per lane per region, as 3x float2 ----
    float* mp = out_means + (long)ray * NW * 3 + 6 * l;
    float* cp = out_covs  + (long)ray * NW * 3 + 6 * l;
    *reinterpret_cast<float2*>(mp)     = make_float2(fmaf(dx, tm[0], ox), fmaf(dy, tm[0], oy));
    *reinterpret_cast<float2*>(mp + 2) = make_float2(fmaf(dz, tm[0], oz), fmaf(dx, tm[1], ox));
    *reinterpret_cast<float2*>(mp + 4) = make_float2(fmaf(dy, tm[1], oy), fmaf(dz, tm[1], oz));
    *reinterpret_cast<float2*>(cp)     = make_float2(fmaf(tv[0], dx2, rv[0] * nx),
                                                     fmaf(tv[0], dy2, rv[0] * ny));
    *reinterpret_cast<float2*>(cp + 2) = make_float2(fmaf(tv[0], dz2, rv[0] * nz),
                                                     fmaf(tv[1], dx2, rv[1] * nx));
    *reinterpret_cast<float2*>(cp + 4) = make_float2(fmaf(tv[1], dy2, rv[1] * ny),
                                                     fmaf(tv[1], dz2, rv[1] * nz));
}

extern "C" void kernel_launch(void* const* d_in, const int* in_sizes, int n_in,
                              void* d_out, int out_size, void* d_ws, size_t ws_size,
                              hipStream_t stream) {
    const float* origins    = (const float*)d_in[0];
    const float* directions = (const float*)d_in[1];
    const float* radii      = (const float*)d_in[2];
    const float* t_vals     = (const float*)d_in[3];
    const float* weights    = (const float*)d_in[4];

    float* out_t     = (float*)d_out;
    float* out_means = out_t + (long)NRAYS * NB;
    float* out_covs  = out_means + (long)NRAYS * NW * 3;

    const int grid = NRAYS / 4;   // 4096 blocks x 256 threads (1 wave per ray)
    mipnerf_wave_kernel<<<grid, 256, 0, stream>>>(
        origins, directions, radii, t_vals, weights, out_t, out_means, out_covs);
}

// Round 3
// 22.542 us; speedup vs baseline: 1.1301x; 1.0782x over previous
//
#include <hip/hip_runtime.h>

#define NRAYS 16384
#define NB 129   // bin edges / samples per ray
#define NW 128   // weights / intervals per ray

// 4 rays per 256-thread block, one wave per ray. All global I/O is
// block-cooperative float4 (every per-block region is 16B-aligned:
// 4*516B t rows, 4*512B weight rows, 4*1536B mean/cov rows).
__global__ __launch_bounds__(256) void mipnerf_block_kernel(
    const float* __restrict__ origins,     // [B,3]
    const float* __restrict__ directions,  // [B,3]
    const float* __restrict__ radii,       // [B,1]
    const float* __restrict__ t_vals,      // [B,129]
    const float* __restrict__ weights,     // [B,128]
    float* __restrict__ out_t,             // [B,129]
    float* __restrict__ out_means,         // [B,128,3]
    float* __restrict__ out_covs)          // [B,128,3]
{
    __shared__ __align__(16) float s_t  [4 * NB];      // original bins
    __shared__ __align__(16) float s_w  [4 * NW];      // raw weights
    __shared__ __align__(16) float s_cdf[4 * NB];
    __shared__ __align__(16) float s_nt [4 * NB];      // resampled t
    __shared__ __align__(16) float s_mean[4 * NW * 3];
    __shared__ __align__(16) float s_cov [4 * NW * 3];

    const int tid = threadIdx.x;
    const int wv  = tid >> 6;      // wave = ray slot
    const int l   = tid & 63;
    const int blk = blockIdx.x;
    const int ray = (blk << 2) + wv;

    // ---- phase 1: block-cooperative float4 staging ----
    if (tid < NB)
        reinterpret_cast<float4*>(s_t)[tid] =
            reinterpret_cast<const float4*>(t_vals + (long)blk * (4 * NB))[tid];
    if (tid < NW)
        reinterpret_cast<float4*>(s_w)[tid] =
            reinterpret_cast<const float4*>(weights + (long)blk * (4 * NW))[tid];
    __syncthreads();

    // ---- phase 2: per-wave compute (wave-synchronous LDS, no block barriers) ----
    const float* wrow = s_w + wv * NW;
    const float w0  = wrow[2 * l];
    const float w1  = wrow[2 * l + 1];
    const float wm1 = (l == 0)  ? w0 : wrow[2 * l - 1];
    const float wp1 = (l == 63) ? w1 : wrow[2 * l + 2];

    // max-blur + resample padding
    const float mx01 = fmaxf(w0, w1);
    const float wb0 = 0.5f * (fmaxf(wm1, w0) + mx01) + 0.01f;
    const float wb1 = 0.5f * (mx01 + fmaxf(w1, wp1)) + 0.01f;

    // wave-wide inclusive scan of pair sums (6 shuffle steps)
    float S = wb0 + wb1;
    #pragma unroll
    for (int off = 1; off < 64; off <<= 1) {
        const float t = __shfl_up(S, off);
        if (l >= off) S += t;
    }
    const float W1 = S;          // prefix through w[2l+1]
    const float W0 = S - wb1;    // prefix through w[2l]
    const float inv_wsum = 1.0f / __shfl(S, 63);
    // eps-pad branch of reference is identically 0: every wb >= 0.01 -> wsum >= 1.28

    float* cdf = s_cdf + wv * NB;
    cdf[2 * l + 1] = fminf(1.0f, W0 * inv_wsum);
    if (l < 63) cdf[2 * l + 2] = fminf(1.0f, W1 * inv_wsum);
    if (l == 0)  cdf[0]      = 0.0f;
    if (l == 63) cdf[NB - 1] = 1.0f;
    __builtin_amdgcn_wave_barrier();   // order cdf writes before searches (same wave)

    const float* bins = s_t + wv * NB;
    const float ueps = 1.0f - 1.1920929e-7f;
    const float step = ueps / 128.0f;

    auto sampleAt = [&](float u) -> float {
        int lo = 0, hi = NB;
        while (lo < hi) {                      // first idx with cdf[idx] > u
            const int mid = (lo + hi) >> 1;
            if (cdf[mid] <= u) lo = mid + 1; else hi = mid;
        }
        const int i1 = lo;                     // in [1,128]
        const int i0 = i1 - 1;
        const float c0 = cdf[i0], c1 = cdf[i1];
        const float b0 = bins[i0], b1 = bins[i1];
        float tt = (u - c0) / (c1 - c0);
        if (tt != tt) tt = 0.0f;               // nan_to_num
        tt = fminf(fmaxf(tt, 0.0f), 1.0f);     // clip (inf -> 1)
        return fmaf(tt, b1 - b0, b0);
    };

    float* ntrow = s_nt + wv * NB;
    ntrow[l]      = sampleAt((float)l * step);
    ntrow[64 + l] = sampleAt((float)(64 + l) * step);
    if (l == 63) ntrow[128] = sampleAt(ueps);
    __builtin_amdgcn_wave_barrier();   // order nt writes before neighbor reads

    const float n0 = ntrow[2 * l];
    const float n1 = ntrow[2 * l + 1];
    const float n2 = ntrow[2 * l + 2];

    // per-ray scalars (lane-uniform -> scalar loads)
    const float dx = directions[ray * 3 + 0];
    const float dy = directions[ray * 3 + 1];
    const float dz = directions[ray * 3 + 2];
    const float ox = origins[ray * 3 + 0];
    const float oy = origins[ray * 3 + 1];
    const float oz = origins[ray * 3 + 2];
    const float rad = radii[ray];
    const float rad2 = rad * rad;
    const float dx2 = dx * dx, dy2 = dy * dy, dz2 = dz * dz;
    const float inv_dms = 1.0f / (dx2 + dy2 + dz2 + 1e-10f);
    const float nxо = 1.0f - dx2 * inv_dms;
    const float nyо = 1.0f - dy2 * inv_dms;
    const float nzо = 1.0f - dz2 * inv_dms;

    float* mrow = s_mean + wv * (NW * 3) + 6 * l;
    float* crow = s_cov  + wv * (NW * 3) + 6 * l;
    const float tt0[2] = { n0, n1 };
    const float tt1[2] = { n1, n2 };
    #pragma unroll
    for (int k = 0; k < 2; ++k) {
        const float mu = 0.5f * (tt0[k] + tt1[k]);
        const float hw = 0.5f * (tt1[k] - tt0[k]);
        const float mu2 = mu * mu, hw2 = hw * hw;
        const float inv_denom = 1.0f / (3.0f * mu2 + hw2);
        const float t_mean = mu + 2.0f * mu * hw2 * inv_denom;
        const float t_var  = hw2 * (1.0f / 3.0f)
                           - (4.0f / 15.0f) * (hw2 * hw2 * (12.0f * mu2 - hw2) * inv_denom * inv_denom);
        const float r_var  = rad2 * (0.25f * mu2 + (5.0f / 12.0f) * hw2
                                     - (4.0f / 15.0f) * hw2 * hw2 * inv_denom);
        mrow[3 * k + 0] = fmaf(dx, t_mean, ox);
        mrow[3 * k + 1] = fmaf(dy, t_mean, oy);
        mrow[3 * k + 2] = fmaf(dz, t_mean, oz);
        crow[3 * k + 0] = fmaf(t_var, dx2, r_var * nxо);
        crow[3 * k + 1] = fmaf(t_var, dy2, r_var * nyо);
        crow[3 * k + 2] = fmaf(t_var, dz2, r_var * nzо);
    }
    __syncthreads();

    // ---- phase 3: block-cooperative float4 writeout ----
    if (tid < NB)
        reinterpret_cast<float4*>(out_t + (long)blk * (4 * NB))[tid] =
            reinterpret_cast<const float4*>(s_nt)[tid];

    float4* om4 = reinterpret_cast<float4*>(out_means + (long)blk * (4 * NW * 3));
    float4* oc4 = reinterpret_cast<float4*>(out_covs  + (long)blk * (4 * NW * 3));
    const float4* sm4 = reinterpret_cast<const float4*>(s_mean);
    const float4* sc4 = reinterpret_cast<const float4*>(s_cov);
    #pragma unroll
    for (int i = tid; i < 4 * NW * 3 / 4; i += 256) {   // 384 float4s, 1.5 per thread
        om4[i] = sm4[i];
        oc4[i] = sc4[i];
    }
}

extern "C" void kernel_launch(void* const* d_in, const int* in_sizes, int n_in,
                              void* d_out, int out_size, void* d_ws, size_t ws_size,
                              hipStream_t stream) {
    const float* origins    = (const float*)d_in[0];
    const float* directions = (const float*)d_in[1];
    const float* radii      = (const float*)d_in[2];
    const float* t_vals     = (const float*)d_in[3];
    const float* weights    = (const float*)d_in[4];

    float* out_t     = (float*)d_out;
    float* out_means = out_t + (long)NRAYS * NB;
    float* out_covs  = out_means + (long)NRAYS * NW * 3;

    const int grid = NRAYS / 4;   // 4096 blocks x 256 threads
    mipnerf_block_kernel<<<grid, 256, 0, stream>>>(
        origins, directions, radii, t_vals, weights, out_t, out_means, out_covs);
}

// Round 4
// 19.558 us; speedup vs baseline: 1.3025x; 1.1525x over previous
//
#include <hip/hip_runtime.h>

#define NRAYS 16384
#define NB 129   // bin edges / samples per ray
#define NW 128   // weights / intervals per ray

// 4 rays per 256-thread block, one wave per ray. All global I/O is
// block-cooperative float4. Inverse-CDF sampling is INVERTED: u is a uniform
// grid, so each interval (lane-resident cdf values from the scan) computes
// which samples it owns -> zero binary searches, no dependent-LDS chains.
__global__ __launch_bounds__(256) void mipnerf_inv_kernel(
    const float* __restrict__ origins,     // [B,3]
    const float* __restrict__ directions,  // [B,3]
    const float* __restrict__ radii,       // [B,1]
    const float* __restrict__ t_vals,      // [B,129]
    const float* __restrict__ weights,     // [B,128]
    float* __restrict__ out_t,             // [B,129]
    float* __restrict__ out_means,         // [B,128,3]
    float* __restrict__ out_covs)          // [B,128,3]
{
    __shared__ __align__(16) float s_t  [4 * NB];      // original bins
    __shared__ __align__(16) float s_w  [4 * NW];      // raw weights
    __shared__ __align__(16) float s_nt [4 * NB];      // resampled t
    __shared__ __align__(16) float s_mean[4 * NW * 3];
    __shared__ __align__(16) float s_cov [4 * NW * 3];

    const int tid = threadIdx.x;
    const int wv  = tid >> 6;      // wave = ray slot
    const int l   = tid & 63;
    const int blk = blockIdx.x;
    const int ray = (blk << 2) + wv;

    // ---- phase 1: block-cooperative float4 staging ----
    if (tid < NB)
        reinterpret_cast<float4*>(s_t)[tid] =
            reinterpret_cast<const float4*>(t_vals + (long)blk * (4 * NB))[tid];
    if (tid < NW)
        reinterpret_cast<float4*>(s_w)[tid] =
            reinterpret_cast<const float4*>(weights + (long)blk * (4 * NW))[tid];
    __syncthreads();

    // ---- phase 2: per-wave compute ----
    const float* wrow = s_w + wv * NW;
    const float w0  = wrow[2 * l];
    const float w1  = wrow[2 * l + 1];
    const float wm1 = (l == 0)  ? w0 : wrow[2 * l - 1];
    const float wp1 = (l == 63) ? w1 : wrow[2 * l + 2];

    // max-blur + resample padding
    const float mx01 = fmaxf(w0, w1);
    const float wb0 = 0.5f * (fmaxf(wm1, w0) + mx01) + 0.01f;
    const float wb1 = 0.5f * (mx01 + fmaxf(w1, wp1)) + 0.01f;

    // wave-wide inclusive scan of pair sums (6 shuffle steps)
    float S = wb0 + wb1;
    #pragma unroll
    for (int off = 1; off < 64; off <<= 1) {
        const float t = __shfl_up(S, off);
        if (l >= off) S += t;
    }
    const float W1 = S;          // prefix through w[2l+1]
    const float W0 = S - wb1;    // prefix through w[2l]
    const float inv_wsum = 1.0f / __shfl(S, 63);
    // eps-pad branch of reference is identically 0: every wb >= 0.01 -> wsum >= 1.28

    // lane-resident cdf values bounding this lane's two intervals (2l, 2l+1)
    const float c_lo  = (l == 0)  ? 0.0f : fminf(1.0f, (W0 - wb0) * inv_wsum);
    const float c_mid = fminf(1.0f, W0 * inv_wsum);
    const float c_hi  = (l == 63) ? 1.0f : fminf(1.0f, W1 * inv_wsum);

    // bin edges for the two intervals
    const float* bins = s_t + wv * NB;
    const float b0 = bins[2 * l];
    const float b1 = bins[2 * l + 1];
    const float b2 = bins[2 * l + 2];

    // sample ownership: interval k owns s in [ceil(cdf[k]/step), ceil(cdf[k+1]/step))
    const float ueps     = 1.0f - 1.1920929e-7f;
    const float step     = ueps / 128.0f;
    const float inv_step = 128.0f / ueps;
    const int s0 = (int)ceilf(c_lo  * inv_step);
    const int s1 = (int)ceilf(c_mid * inv_step);
    const int s2 = (int)ceilf(c_hi  * inv_step);   // c_hi=1 -> ceil(128.00002)=129 covers s=128

    float* ntrow = s_nt + wv * NB;
    {
        const float inv_d = 1.0f / (c_mid - c_lo);   // >0 whenever loop non-empty
        const float db = b1 - b0;
        for (int s = s0; s < s1; ++s) {
            float tt = ((float)s * step - c_lo) * inv_d;
            tt = fminf(fmaxf(tt, 0.0f), 1.0f);
            ntrow[s] = fmaf(tt, db, b0);
        }
    }
    {
        const float inv_d = 1.0f / (c_hi - c_mid);
        const float db = b2 - b1;
        for (int s = s1; s < s2; ++s) {
            float tt = ((float)s * step - c_mid) * inv_d;
            tt = fminf(fmaxf(tt, 0.0f), 1.0f);
            ntrow[s] = fmaf(tt, db, b1);
        }
    }
    __builtin_amdgcn_wave_barrier();   // order nt scatter before neighbor reads (same wave)

    const float n0 = ntrow[2 * l];
    const float n1 = ntrow[2 * l + 1];
    const float n2 = ntrow[2 * l + 2];

    // per-ray scalars (lane-uniform -> scalar loads)
    const float dx = directions[ray * 3 + 0];
    const float dy = directions[ray * 3 + 1];
    const float dz = directions[ray * 3 + 2];
    const float ox = origins[ray * 3 + 0];
    const float oy = origins[ray * 3 + 1];
    const float oz = origins[ray * 3 + 2];
    const float rad = radii[ray];
    const float rad2 = rad * rad;
    const float dx2 = dx * dx, dy2 = dy * dy, dz2 = dz * dz;
    const float inv_dms = 1.0f / (dx2 + dy2 + dz2 + 1e-10f);
    const float nullx = 1.0f - dx2 * inv_dms;
    const float nully = 1.0f - dy2 * inv_dms;
    const float nullz = 1.0f - dz2 * inv_dms;

    float* mrow = s_mean + wv * (NW * 3) + 6 * l;
    float* crow = s_cov  + wv * (NW * 3) + 6 * l;
    const float tt0[2] = { n0, n1 };
    const float tt1[2] = { n1, n2 };
    #pragma unroll
    for (int k = 0; k < 2; ++k) {
        const float mu = 0.5f * (tt0[k] + tt1[k]);
        const float hw = 0.5f * (tt1[k] - tt0[k]);
        const float mu2 = mu * mu, hw2 = hw * hw;
        const float inv_denom = 1.0f / (3.0f * mu2 + hw2);
        const float t_mean = mu + 2.0f * mu * hw2 * inv_denom;
        const float t_var  = hw2 * (1.0f / 3.0f)
                           - (4.0f / 15.0f) * (hw2 * hw2 * (12.0f * mu2 - hw2) * inv_denom * inv_denom);
        const float r_var  = rad2 * (0.25f * mu2 + (5.0f / 12.0f) * hw2
                                     - (4.0f / 15.0f) * hw2 * hw2 * inv_denom);
        mrow[3 * k + 0] = fmaf(dx, t_mean, ox);
        mrow[3 * k + 1] = fmaf(dy, t_mean, oy);
        mrow[3 * k + 2] = fmaf(dz, t_mean, oz);
        crow[3 * k + 0] = fmaf(t_var, dx2, r_var * nullx);
        crow[3 * k + 1] = fmaf(t_var, dy2, r_var * nully);
        crow[3 * k + 2] = fmaf(t_var, dz2, r_var * nullz);
    }
    __syncthreads();

    // ---- phase 3: block-cooperative float4 writeout ----
    if (tid < NB)
        reinterpret_cast<float4*>(out_t + (long)blk * (4 * NB))[tid] =
            reinterpret_cast<const float4*>(s_nt)[tid];

    float4* om4 = reinterpret_cast<float4*>(out_means + (long)blk * (4 * NW * 3));
    float4* oc4 = reinterpret_cast<float4*>(out_covs  + (long)blk * (4 * NW * 3));
    const float4* sm4 = reinterpret_cast<const float4*>(s_mean);
    const float4* sc4 = reinterpret_cast<const float4*>(s_cov);
    #pragma unroll
    for (int i = tid; i < 4 * NW * 3 / 4; i += 256) {   // 384 float4s, 1.5 per thread
        om4[i] = sm4[i];
        oc4[i] = sc4[i];
    }
}

extern "C" void kernel_launch(void* const* d_in, const int* in_sizes, int n_in,
                              void* d_out, int out_size, void* d_ws, size_t ws_size,
                              hipStream_t stream) {
    const float* origins    = (const float*)d_in[0];
    const float* directions = (const float*)d_in[1];
    const float* radii      = (const float*)d_in[2];
    const float* t_vals     = (const float*)d_in[3];
    const float* weights    = (const float*)d_in[4];

    float* out_t     = (float*)d_out;
    float* out_means = out_t + (long)NRAYS * NB;
    float* out_covs  = out_means + (long)NRAYS * NW * 3;

    const int grid = NRAYS / 4;   // 4096 blocks x 256 threads
    mipnerf_inv_kernel<<<grid, 256, 0, stream>>>(
        origins, directions, radii, t_vals, weights, out_t, out_means, out_covs);
}

// Round 5
// 19.284 us; speedup vs baseline: 1.3211x; 1.0142x over previous
//
#include <hip/hip_runtime.h>

#define NRAYS 16384
#define NB 129   // bin edges / samples per ray
#define NW 128   // weights / intervals per ray

// Fully wave-independent: one wave per ray, 4 waves per 256-thread block,
// ZERO __syncthreads. Inputs loaded directly to registers (float2 weights,
// neighbor-only scalar bins). LDS used only per-wave: nt scatter target and
// means/covs layout transform for float4 writeout, ordered by wave_barrier.
__global__ __launch_bounds__(256) void mipnerf_waveind_kernel(
    const float* __restrict__ origins,     // [B,3]
    const float* __restrict__ directions,  // [B,3]
    const float* __restrict__ radii,       // [B,1]
    const float* __restrict__ t_vals,      // [B,129]
    const float* __restrict__ weights,     // [B,128]
    float* __restrict__ out_t,             // [B,129]
    float* __restrict__ out_means,         // [B,128,3]
    float* __restrict__ out_covs)          // [B,128,3]
{
    __shared__ __align__(16) float s_nt  [4][NB + 3];   // 132 floats/row -> rows stay 16B-aligned
    __shared__ __align__(16) float s_mean[4][NW * 3];   // 1536B rows
    __shared__ __align__(16) float s_cov [4][NW * 3];

    const int tid = threadIdx.x;
    const int wv  = tid >> 6;      // wave = ray slot
    const int l   = tid & 63;
    const int ray = (blockIdx.x << 2) + wv;

    // ---- direct register loads (no staging) ----
    const float2 wp = *reinterpret_cast<const float2*>(weights + (long)ray * NW + 2 * l);
    const float w0 = wp.x, w1 = wp.y;              // w[2l], w[2l+1]
    const float* trow = t_vals + (long)ray * NB;
    const float b0 = trow[2 * l];                  // neighbor-only bin access
    const float b1 = trow[2 * l + 1];
    const float b2 = trow[2 * l + 2];

    // per-ray scalars (uniform per wave -> broadcast loads)
    const float dx = directions[ray * 3 + 0];
    const float dy = directions[ray * 3 + 1];
    const float dz = directions[ray * 3 + 2];
    const float ox = origins[ray * 3 + 0];
    const float oy = origins[ray * 3 + 1];
    const float oz = origins[ray * 3 + 2];
    const float rad = radii[ray];

    // ---- max-blur + resample padding (neighbors via shuffle) ----
    float wm1 = __shfl_up(w1, 1);   if (l == 0)  wm1 = w0;   // w[2l-1]
    float wp1 = __shfl_down(w0, 1); if (l == 63) wp1 = w1;   // w[2l+2]
    const float mx01 = fmaxf(w0, w1);
    const float wb0 = 0.5f * (fmaxf(wm1, w0) + mx01) + 0.01f;
    const float wb1 = 0.5f * (mx01 + fmaxf(w1, wp1)) + 0.01f;

    // ---- wave-wide inclusive scan of pair sums (6 shuffle steps) ----
    float S = wb0 + wb1;
    #pragma unroll
    for (int off = 1; off < 64; off <<= 1) {
        const float t = __shfl_up(S, off);
        if (l >= off) S += t;
    }
    const float W1 = S;          // prefix through w[2l+1]
    const float W0 = S - wb1;    // prefix through w[2l]
    const float inv_wsum = 1.0f / __shfl(S, 63);
    // eps-pad branch of reference is identically 0: every wb >= 0.01 -> wsum >= 1.28

    // lane-resident cdf values bounding intervals 2l and 2l+1
    const float c_lo  = (l == 0)  ? 0.0f : fminf(1.0f, (W0 - wb0) * inv_wsum);
    const float c_mid = fminf(1.0f, W0 * inv_wsum);
    const float c_hi  = (l == 63) ? 1.0f : fminf(1.0f, W1 * inv_wsum);

    // ---- inverted sampling: interval k owns s in [ceil(cdf[k]/step), ceil(cdf[k+1]/step)) ----
    const float ueps     = 1.0f - 1.1920929e-7f;
    const float step     = ueps / 128.0f;
    const float inv_step = 128.0f / ueps;
    const int s0 = (int)ceilf(c_lo  * inv_step);
    const int s1 = (int)ceilf(c_mid * inv_step);
    const int s2 = (int)ceilf(c_hi  * inv_step);   // c_hi=1 -> 129, covers s=128

    float* ntrow = s_nt[wv];
    {
        const float inv_d = 1.0f / (c_mid - c_lo);
        const float db = b1 - b0;
        for (int s = s0; s < s1; ++s) {
            float tt = ((float)s * step - c_lo) * inv_d;
            tt = fminf(fmaxf(tt, 0.0f), 1.0f);
            ntrow[s] = fmaf(tt, db, b0);
        }
    }
    {
        const float inv_d = 1.0f / (c_hi - c_mid);
        const float db = b2 - b1;
        for (int s = s1; s < s2; ++s) {
            float tt = ((float)s * step - c_mid) * inv_d;
            tt = fminf(fmaxf(tt, 0.0f), 1.0f);
            ntrow[s] = fmaf(tt, db, b1);
        }
    }
    __builtin_amdgcn_wave_barrier();   // order scatter before neighbor reads (same wave)

    const float n0 = ntrow[2 * l];
    const float n1 = ntrow[2 * l + 1];
    const float n2 = ntrow[2 * l + 2];

    const float rad2 = rad * rad;
    const float dx2 = dx * dx, dy2 = dy * dy, dz2 = dz * dz;
    const float inv_dms = 1.0f / (dx2 + dy2 + dz2 + 1e-10f);
    const float nullx = 1.0f - dx2 * inv_dms;
    const float nully = 1.0f - dy2 * inv_dms;
    const float nullz = 1.0f - dz2 * inv_dms;

    // ---- conical frustum -> Gaussian for intervals 2l, 2l+1 ----
    float* mrow = s_mean[wv] + 6 * l;
    float* crow = s_cov[wv]  + 6 * l;
    const float tt0[2] = { n0, n1 };
    const float tt1[2] = { n1, n2 };
    #pragma unroll
    for (int k = 0; k < 2; ++k) {
        const float mu = 0.5f * (tt0[k] + tt1[k]);
        const float hw = 0.5f * (tt1[k] - tt0[k]);
        const float mu2 = mu * mu, hw2 = hw * hw;
        const float inv_denom = 1.0f / (3.0f * mu2 + hw2);
        const float t_mean = mu + 2.0f * mu * hw2 * inv_denom;
        const float t_var  = hw2 * (1.0f / 3.0f)
                           - (4.0f / 15.0f) * (hw2 * hw2 * (12.0f * mu2 - hw2) * inv_denom * inv_denom);
        const float r_var  = rad2 * (0.25f * mu2 + (5.0f / 12.0f) * hw2
                                     - (4.0f / 15.0f) * hw2 * hw2 * inv_denom);
        mrow[3 * k + 0] = fmaf(dx, t_mean, ox);
        mrow[3 * k + 1] = fmaf(dy, t_mean, oy);
        mrow[3 * k + 2] = fmaf(dz, t_mean, oz);
        crow[3 * k + 0] = fmaf(t_var, dx2, r_var * nullx);
        crow[3 * k + 1] = fmaf(t_var, dy2, r_var * nully);
        crow[3 * k + 2] = fmaf(t_var, dz2, r_var * nullz);
    }
    __builtin_amdgcn_wave_barrier();   // order mean/cov writes before float4 re-read (same wave)

    // ---- per-wave coalesced writeout ----
    float* po = out_t + (long)ray * NB;
    po[l]      = ntrow[l];
    po[64 + l] = ntrow[64 + l];
    if (l == 0) po[128] = ntrow[128];

    float4* pm = reinterpret_cast<float4*>(out_means + (long)ray * (NW * 3));  // ray*1536B, 16B-aligned
    float4* pc = reinterpret_cast<float4*>(out_covs  + (long)ray * (NW * 3));
    const float4* sm = reinterpret_cast<const float4*>(s_mean[wv]);
    const float4* sc = reinterpret_cast<const float4*>(s_cov[wv]);
    pm[l] = sm[l];
    pc[l] = sc[l];
    if (l < 32) {
        pm[64 + l] = sm[64 + l];
        pc[64 + l] = sc[64 + l];
    }
}

extern "C" void kernel_launch(void* const* d_in, const int* in_sizes, int n_in,
                              void* d_out, int out_size, void* d_ws, size_t ws_size,
                              hipStream_t stream) {
    const float* origins    = (const float*)d_in[0];
    const float* directions = (const float*)d_in[1];
    const float* radii      = (const float*)d_in[2];
    const float* t_vals     = (const float*)d_in[3];
    const float* weights    = (const float*)d_in[4];

    float* out_t     = (float*)d_out;
    float* out_means = out_t + (long)NRAYS * NB;
    float* out_covs  = out_means + (long)NRAYS * NW * 3;

    const int grid = NRAYS / 4;   // 4096 blocks x 256 threads, 1 wave per ray
    mipnerf_waveind_kernel<<<grid, 256, 0, stream>>>(
        origins, directions, radii, t_vals, weights, out_t, out_means, out_covs);
}